// Round 8
// baseline (217.700 us; speedup 1.0000x reference)
//
#include <hip/hip_runtime.h>

// WeightedTensorProduct: N=16384 nodes, F=128, ranks 0..3 (sizes 1,3,9,27).
// x,y: [N, 5120] f32 (row: [128] | [128][3] | [128][9] | [128][27]).
// weights: [23][128] f32. out: [N, 5120] f32.
//
// Persistent double-buffered pipeline: 1024 blocks x 128 threads, each block
// owns 32 nodes of one feature-half (64 features). Per iteration, the NEXT
// node's global->LDS DMA is issued before computing the CURRENT node, with a
// counted s_waitcnt vmcnt(15) (never a full drain in the loop) so HBM loads
// stay in flight during compute -> fixes round 7's 60% BW duty cycle.
// Raw s_barrier + explicit lgkmcnt waits (no __syncthreads -> no vmcnt(0)).

#define FF 128
#define ROW 5120
#define HALFROW 2560   // floats per half-node row (64 features x 40)

typedef float floatx4 __attribute__((ext_vector_type(4)));

__device__ __constant__ float NORMS[23] = {
    1.0f, 1.0f, 2.0f/3.0f, 0.4f,                          // (0,0,0)(1,1,0)(2,2,0)(3,3,0)
    1.0f, 1.0f, 1.0f, 1.0f, 2.0f/3.0f, 2.0f/3.0f,         // l3=1 paths
    1.0f, 0.75f, 1.0f, 1.0f, 1.0f, 1.0f, 0.75f,           // l3=2 paths
    1.0f, 5.0f/9.0f, 5.0f/9.0f, 5.0f/6.0f, 1.0f, 5.0f/6.0f // l3=3 paths
};

#define GL2LDS(g, l)  __builtin_amdgcn_global_load_lds(                      \
        (const __attribute__((address_space(1))) void*)(g),                  \
        (__attribute__((address_space(3))) void*)(l), 16, 0, 0)

__global__ __launch_bounds__(128, 2) void wtp_kernel(
    const float* __restrict__ x, const float* __restrict__ y,
    const float* __restrict__ w, float* __restrict__ out, int n_nodes)
{
    __shared__ float buf[2][2 * HALFROW];   // 2 x 20 KB double buffer

    const int tid   = threadIdx.x;
    const int f     = tid & 63;               // local feature
    const int half  = tid >> 6;               // wave 0 -> l3=0,1,2 ; wave 1 -> l3=3
    const int wbase = half * 256;             // wave-uniform LDS float offset

    const int bslot = blockIdx.x & 511;
    const int fbase = (blockIdx.x >> 9) << 6; // 0 or 64
    const int chunk = n_nodes >> 9;           // nodes per block (32)
    const int first = bslot * chunk;

    // per-lane global offsets for the 5 DMA/store issues (packed half-row)
    int goff[5];
    #pragma unroll
    for (int i = 0; i < 5; ++i) {
        const int o = i * 512 + tid * 4;
        int r;
        if      (o < 64)  r = fbase        + o;
        else if (o < 256) r = 128 + fbase*3  + (o - 64);
        else if (o < 832) r = 512 + fbase*9  + (o - 256);
        else              r = 1664 + fbase*27 + (o - 832);
        goff[i] = r;
    }

    // ---- prologue: stage node `first` into buf[0] ----
    {
        const float* xr = x + (size_t)first * ROW;
        const float* yr = y + (size_t)first * ROW;
        #pragma unroll
        for (int i = 0; i < 5; ++i) {
            GL2LDS(xr + goff[i], &buf[0][i * 512 + wbase]);
            GL2LDS(yr + goff[i], &buf[0][HALFROW + i * 512 + wbase]);
        }
    }

    // weights (overlap the prologue DMA window); compiler guards c[] uses
    float c[23];
    #pragma unroll
    for (int p = 0; p < 23; ++p) c[p] = NORMS[p] * w[p * FF + fbase + f];

    int cur = 0;
    for (int k = 0; k < chunk; ++k) {
        const int node = first + k;

        // ---- prefetch next node into the other buffer, counted wait ----
        if (k + 1 < chunk) {
            const float* xr = x + (size_t)(node + 1) * ROW;
            const float* yr = y + (size_t)(node + 1) * ROW;
            float* nb = &buf[cur ^ 1][0];
            #pragma unroll
            for (int i = 0; i < 5; ++i) {
                GL2LDS(xr + goff[i], nb + i * 512 + wbase);
                GL2LDS(yr + goff[i], nb + HALFROW + i * 512 + wbase);
            }
            if (k == 0) {
                // retire prologue stage + all 23 weight loads; keep the 10 fresh
                asm volatile("s_waitcnt vmcnt(10)" ::: "memory");
            } else {
                // outstanding: [10 cur-loads][5 fresh NT stores][10 new loads]
                // vmcnt(15) retires the cur-loads, leaves stores+prefetch in flight
                asm volatile("s_waitcnt vmcnt(15)" ::: "memory");
            }
        } else {
            asm volatile("s_waitcnt vmcnt(0)" ::: "memory");
        }
        __builtin_amdgcn_s_barrier();      // buf[cur] fully staged, all waves

        // ---- compute from buf[cur]: rank 0..2 -> regs, rank 3 from LDS ----
        const float* bx = &buf[cur][0];
        const float* by = &buf[cur][HALFROW];
        const float x0 = bx[f], y0 = by[f];
        float x1[3], y1[3], x2[9], y2[9];
        #pragma unroll
        for (int j = 0; j < 3; ++j)  x1[j] = bx[64  + f*3 + j];
        #pragma unroll
        for (int j = 0; j < 3; ++j)  y1[j] = by[64  + f*3 + j];
        #pragma unroll
        for (int j = 0; j < 9; ++j)  x2[j] = bx[256 + f*9 + j];
        #pragma unroll
        for (int j = 0; j < 9; ++j)  y2[j] = by[256 + f*9 + j];

        const float* bx3 = bx + 832 + f*27;   // stride 27 (odd) -> conflict-free
        const float* by3 = by + 832 + f*27;

        float o0, o1[3], o2[9], o3[27];

        if (half == 0) {
            // ---- l3 = 0 ----
            {
                float acc = c[0] * (x0 * y0);
                float d3 = 0.f;
                #pragma unroll
                for (int u = 0; u < 3; ++u) d3 += x1[u] * y1[u];
                acc += c[1] * d3;
                float d9 = 0.f;
                #pragma unroll
                for (int t = 0; t < 9; ++t) d9 += x2[t] * y2[t];
                acc += c[2] * d9;
                float d27 = 0.f;
                #pragma unroll
                for (int t = 0; t < 27; ++t) d27 += bx3[t] * by3[t];
                acc += c[3] * d27;
                o0 = acc;
            }
            // ---- l3 = 1 ----
            #pragma unroll
            for (int d = 0; d < 3; ++d) {
                float acc = c[4] * (x0 * y1[d]) + c[5] * (x1[d] * y0);
                float s6 = 0.f, s7 = 0.f, s8 = 0.f, s9 = 0.f;
                #pragma unroll
                for (int u = 0; u < 3; ++u) s6 += x1[u] * y2[u*3 + d];     // (1,2,1)
                #pragma unroll
                for (int u = 0; u < 3; ++u) s7 += x2[d*3 + u] * y1[u];     // (2,1,1)
                #pragma unroll
                for (int t = 0; t < 9; ++t) s8 += x2[t] * by3[t*3 + d];    // (2,3,1)
                #pragma unroll
                for (int t = 0; t < 9; ++t) s9 += bx3[d*9 + t] * y2[t];    // (3,2,1)
                o1[d] = acc + c[6]*s6 + c[7]*s7 + c[8]*s8 + c[9]*s9;
            }
            // ---- l3 = 2 ----  (t = a*3 + d)
            #pragma unroll
            for (int t = 0; t < 9; ++t) {
                const int a = t / 3, d = t % 3;
                float acc = c[10] * (x0 * y2[t]) + c[11] * (x1[a] * y1[d])
                          + c[13] * (x2[t] * y0);
                float s12 = 0.f, s14 = 0.f, s15 = 0.f, s16 = 0.f;
                #pragma unroll
                for (int u = 0; u < 3; ++u) s12 += x1[u] * by3[u*9 + t];       // (1,3,2)
                #pragma unroll
                for (int u = 0; u < 3; ++u) s14 += x2[a*3 + u] * y2[u*3 + d];  // (2,2,2)
                #pragma unroll
                for (int u = 0; u < 3; ++u) s15 += bx3[t*3 + u] * y1[u];       // (3,1,2)
                #pragma unroll
                for (int s = 0; s < 9; ++s) s16 += bx3[a*9 + s] * by3[s*3 + d];// (3,3,2)
                o2[t] = acc + c[12]*s12 + c[14]*s14 + c[15]*s15 + c[16]*s16;
            }
        } else {
            // ---- l3 = 3 ----  (q = a*9 + t9, also q = r*3 + e)
            #pragma unroll
            for (int q = 0; q < 27; ++q) {
                const int a = q / 9, t9 = q % 9, r = q / 3, e = q % 3;
                float acc = c[17] * (x0 * by3[q]) + c[18] * (x1[a] * y2[t9])
                          + c[19] * (x2[r] * y1[e]) + c[21] * (bx3[q] * y0);
                float s20 = 0.f, s22 = 0.f;
                #pragma unroll
                for (int u = 0; u < 3; ++u) s20 += x2[a*3 + u] * by3[u*9 + t9]; // (2,3,3)
                #pragma unroll
                for (int u = 0; u < 3; ++u) s22 += bx3[r*3 + u] * y2[u*3 + e];  // (3,2,3)
                o3[q] = acc + c[20]*s20 + c[22]*s22;
            }
        }

        asm volatile("s_waitcnt lgkmcnt(0)" ::: "memory");
        __builtin_amdgcn_s_barrier();      // all reads of buf[cur] complete

        // ---- stage outputs into buf[cur] x-region (odd strides) ----
        float* B = &buf[cur][0];
        if (half == 0) {
            B[f] = o0;
            #pragma unroll
            for (int d = 0; d < 3; ++d) B[64  + f*3 + d] = o1[d];
            #pragma unroll
            for (int t = 0; t < 9; ++t) B[256 + f*9 + t] = o2[t];
        } else {
            #pragma unroll
            for (int q = 0; q < 27; ++q) B[832 + f*27 + q] = o3[q];
        }
        asm volatile("s_waitcnt lgkmcnt(0)" ::: "memory");
        __builtin_amdgcn_s_barrier();      // outputs visible to all waves

        // ---- coalesced NT float4 store (same offsets as the DMA) ----
        float* orow = out + (size_t)node * ROW;
        #pragma unroll
        for (int i = 0; i < 5; ++i) {
            floatx4 v = *(const floatx4*)(B + i * 512 + tid * 4);
            __builtin_nontemporal_store(v, (floatx4*)(orow + goff[i]));
        }
        asm volatile("s_waitcnt lgkmcnt(0)" ::: "memory");
        __builtin_amdgcn_s_barrier();      // store-reads of buf[cur] done before
                                           // next iter's DMA overwrites it
        cur ^= 1;
    }
}

extern "C" void kernel_launch(void* const* d_in, const int* in_sizes, int n_in,
                              void* d_out, int out_size, void* d_ws, size_t ws_size,
                              hipStream_t stream) {
    const float* x = (const float*)d_in[0];
    const float* y = (const float*)d_in[1];
    const float* w = (const float*)d_in[2];
    float* out = (float*)d_out;

    const int n_nodes = in_sizes[0] / ROW;       // 16384
    dim3 grid(1024), block(128);                 // 512 blocks per feature-half
    hipLaunchKernelGGL(wtp_kernel, grid, block, 0, stream, x, y, w, out, n_nodes);
}